// Round 1
// baseline (340.262 us; speedup 1.0000x reference)
//
#include <hip/hip_runtime.h>

// Problem constants
#define NIMG 32
#define H 112
#define W 112
#define CI 64
#define CO 128
// K = 3*3*64 = 576 -> 18 K-steps of 32

typedef __attribute__((ext_vector_type(8))) __bf16 bf16x8;
typedef __attribute__((ext_vector_type(4))) float f32x4;
typedef __attribute__((ext_vector_type(4))) short short4v;
typedef __attribute__((ext_vector_type(4))) int int4v;

// Quantize to 8-bit fixed point; return INTEGER value (-128..127) as bf16 bits.
// Exact: ints of magnitude <=128 are exactly representable in bf16.
__device__ __forceinline__ short q8bits(float v) {
    float t = rintf(v * 128.0f);              // round-half-even == np.round
    t = fminf(fmaxf(t, -128.0f), 127.0f);
    union { float f; unsigned u; } cv; cv.f = t;
    return (short)(cv.u >> 16);               // exact fp32->bf16 (int-valued)
}

// Weights HWIO [576][128] fp32 -> MFMA B-frag order (verified exact in R1).
// bp[(((kk*8 + nt)*64 + lane)*8) + j] = q(w[(kk*32 + (lane>>4)*8 + j)*128 + nt*16 + (lane&15)])
__global__ __launch_bounds__(256) void quant_pack_w(const float* __restrict__ w,
                                                    short* __restrict__ bp) {
    int idx = blockIdx.x * 256 + threadIdx.x;   // grid sized exactly 73728
    int j    = idx & 7;
    int lane = (idx >> 3) & 63;
    int nt   = (idx >> 9) & 7;
    int kt   = idx >> 12;
    int k = kt * 32 + (lane >> 4) * 8 + j;
    int n = nt * 16 + (lane & 15);
    bp[idx] = q8bits(w[k * CO + n]);
}

// Activation prepass: fp32 NHWC -> bf16-int NHWC (same layout), 8 elems/thread.
__global__ __launch_bounds__(256) void quant_x(const float* __restrict__ x,
                                               short* __restrict__ xq) {
    size_t i = ((size_t)blockIdx.x * 256 + threadIdx.x) * 8;
    float4 v0 = *(const float4*)&x[i];
    float4 v1 = *(const float4*)&x[i + 4];
    short4v a, b;
    a.x = q8bits(v0.x); a.y = q8bits(v0.y); a.z = q8bits(v0.z); a.w = q8bits(v0.w);
    b.x = q8bits(v1.x); b.y = q8bits(v1.y); b.z = q8bits(v1.z); b.w = q8bits(v1.w);
    *(short4v*)&xq[i]     = a;
    *(short4v*)&xq[i + 4] = b;
}

// ---------------- Main conv: 1 output row per block, 4 waves ----------------
// Wave w: 112 m (whole row) x 32 co (co quarter = w*32), acc[7][2] = 56 VGPRs.
// LDS: 3 input rows x 114 cols x 64ci bf16, XOR-swizzled chunks (same layout
// as prior verified kernel):
//   phys addr (shorts) = row*LROW + c*64 + ((chunk_log ^ (c&7)) * 8)
// DMA writes lane l -> base + l*16B (c = 1+i*8+(l>>3), chunk_phys = l&7),
// so lane l sources global chunk (l&7)^(c&7) -> swizzle for free, coalesced.
// 43.8 KB LDS + <=168 VGPR -> 3 blocks/CU = 3 waves/SIMD (was 2).
#define LROW 7296   // 114*64 shorts = 14592 B per row slot

__global__ __launch_bounds__(256, 3) void conv1r(const short* __restrict__ xq,
                                                 const short* __restrict__ bp,
                                                 float* __restrict__ out) {
    __shared__ short xs[3 * LROW];              // 43776 B -> 3 blocks/CU
    int bid = blockIdx.x;
    int n = bid / H;
    int h = bid - n * H;
    int tid  = threadIdx.x;
    int lane = tid & 63;
    int wave = tid >> 6;

    // ---- stage: 3 input rows, 14 DMA chunk-groups per row, split over waves ----
    int lc = lane >> 3;                         // local col within 8-col chunk group
    int jp = lane & 7;                          // physical 16B chunk within col
    #pragma unroll
    for (int row = 0; row < 3; ++row) {
        short* ldsrow = &xs[row * LROW];
        int hr = h - 1 + row;
        if ((unsigned)hr < (unsigned)H) {
            const short* grow = xq + ((size_t)(n * H + hr) * W) * CI;
            for (int i = wave; i < 14; i += 4) {
                int gc = i * 8 + lc;            // global col 0..111
                int jl = jp ^ ((gc + 1) & 7);   // logical chunk to fetch
                const short* g = grow + gc * 64 + jl * 8;
                __builtin_amdgcn_global_load_lds(
                    (const __attribute__((address_space(1))) void*)g,
                    (__attribute__((address_space(3))) void*)(ldsrow + 64 + i * 512),
                    16, 0, 0);
            }
        } else {
            for (int t = tid; t < 912; t += 256)    // zero whole row (boundary)
                *(int4v*)&ldsrow[t * 8] = (int4v){0, 0, 0, 0};
        }
    }
    if (wave == 3 && lane < 48) {               // zero halo cols c=0 and c=113, 3 rows
        int row = lane >> 4;
        int c = (lane & 8) ? 113 : 0;
        *(int4v*)&xs[row * LROW + c * 64 + (lane & 7) * 8] = (int4v){0, 0, 0, 0};
    }
    __syncthreads();

    // ---- implicit GEMM: wave = 112 m x 32 co, K=576 ----
    int lane15 = lane & 15;
    int hi     = lane >> 4;                     // 0..3
    int nt0    = wave * 2;                      // first of 2 n-tiles (co = wave*32)

    const bf16x8* bfr = (const bf16x8*)bp;

    f32x4 acc[7][2];
    #pragma unroll
    for (int mt = 0; mt < 7; ++mt) {
        acc[mt][0] = (f32x4){0.f, 0.f, 0.f, 0.f};
        acc[mt][1] = (f32x4){0.f, 0.f, 0.f, 0.f};
    }

    #pragma unroll
    for (int r = 0; r < 3; ++r) {
        int rbase = r * LROW;
        #pragma unroll
        for (int s = 0; s < 3; ++s) {
            int cb = s + lane15;                // LDS col for m = lane15 (mt adds 16)
            int sx = cb & 7;                    // swizzle key (mt*16 ≡ 0 mod 8)
            int abase = rbase + cb * 64;
            #pragma unroll
            for (int kh = 0; kh < 2; ++kh) {
                int kk = (r * 3 + s) * 2 + kh;
                bf16x8 b0 = bfr[(kk * 8 + nt0    ) * 64 + lane];
                bf16x8 b1 = bfr[(kk * 8 + nt0 + 1) * 64 + lane];
                int joff = ((kh * 4 + hi) ^ sx) * 8;
                #pragma unroll
                for (int mt = 0; mt < 7; ++mt) {
                    bf16x8 a = *(const bf16x8*)&xs[abase + mt * 1024 + joff];
                    acc[mt][0] = __builtin_amdgcn_mfma_f32_16x16x32_bf16(a, b0, acc[mt][0], 0, 0, 0);
                    acc[mt][1] = __builtin_amdgcn_mfma_f32_16x16x32_bf16(a, b1, acc[mt][1], 0, 0, 0);
                }
            }
        }
    }

    // ---- epilogue: out = floor(S/128)/128 (exact) ----
    float* orow = out + (size_t)((n * H + h) * W) * CO;
    int co0  = wave * 32 + lane15;
    int rowb = hi * 4;
    #pragma unroll
    for (int mt = 0; mt < 7; ++mt)
        #pragma unroll
        for (int t = 0; t < 2; ++t)
            #pragma unroll
            for (int rg = 0; rg < 4; ++rg) {
                int m = mt * 16 + rowb + rg;
                orow[m * CO + co0 + t * 16] =
                    floorf(acc[mt][t][rg] * 0.0078125f) * 0.0078125f;
            }
}

// ---------------- R1 fallback (ws too small for xq): verified exact ----------------
#define LDSW 114
#define LDST 72
__global__ __launch_bounds__(256, 3) void conv_fb(const float* __restrict__ x,
                                                  const short* __restrict__ bp,
                                                  float* __restrict__ out) {
    __shared__ short xs[3 * LDSW * LDST];
    int bid = blockIdx.x;
    int n = bid / H;
    int h = bid - n * H;
    int tid = threadIdx.x;
    const float* xin = x + (size_t)n * (H * W * CI);
    for (int r = 0; r < 3; ++r) {
        int hrow = h + r - 1;
        bool rowok = ((unsigned)hrow < (unsigned)H);
        const float* srow = xin + (size_t)hrow * (W * CI);
        for (int t = tid; t < LDSW * 16; t += 256) {
            int c = t >> 4;
            int ci4 = (t & 15) << 2;
            int wcol = c - 1;
            float4 v = {0.f, 0.f, 0.f, 0.f};
            if (rowok && (unsigned)wcol < (unsigned)W)
                v = *(const float4*)&srow[wcol * CI + ci4];
            short4v sv;
            sv.x = q8bits(v.x); sv.y = q8bits(v.y);
            sv.z = q8bits(v.z); sv.w = q8bits(v.w);
            *(short4v*)&xs[(r * LDSW + c) * LDST + ci4] = sv;
        }
    }
    __syncthreads();
    int lane = tid & 63;
    int wave = tid >> 6;
    int laneoff = (lane & 15) * LDST + (lane >> 4) * 8;
    const bf16x8* bfr = (const bf16x8*)bp;
    int nt0 = wave * 2;
    f32x4 acc[7][2];
    #pragma unroll
    for (int mt = 0; mt < 7; ++mt) {
        acc[mt][0] = (f32x4){0.f, 0.f, 0.f, 0.f};
        acc[mt][1] = (f32x4){0.f, 0.f, 0.f, 0.f};
    }
    #pragma unroll
    for (int kk = 0; kk < 18; ++kk) {
        int rs = kk >> 1;
        int r = rs / 3;
        int s = rs - r * 3;
        bf16x8 b0 = bfr[(kk * 8 + nt0    ) * 64 + lane];
        bf16x8 b1 = bfr[(kk * 8 + nt0 + 1) * 64 + lane];
        int abase = (r * LDSW + s) * LDST + (kk & 1) * 32 + laneoff;
        #pragma unroll
        for (int mt = 0; mt < 7; ++mt) {
            bf16x8 a = *(const bf16x8*)&xs[abase + mt * 16 * LDST];
            acc[mt][0] = __builtin_amdgcn_mfma_f32_16x16x32_bf16(a, b0, acc[mt][0], 0, 0, 0);
            acc[mt][1] = __builtin_amdgcn_mfma_f32_16x16x32_bf16(a, b1, acc[mt][1], 0, 0, 0);
        }
    }
    float* orow = out + (size_t)(n * H + h) * (W * CO);
    int colc = wave * 32 + (lane & 15);
    int rowb = (lane >> 4) * 4;
    #pragma unroll
    for (int mt = 0; mt < 7; ++mt)
        #pragma unroll
        for (int t2 = 0; t2 < 2; ++t2)
            #pragma unroll
            for (int rg = 0; rg < 4; ++rg) {
                int m = mt * 16 + rowb + rg;
                orow[m * CO + colc + t2 * 16] =
                    floorf(acc[mt][t2][rg] * 0.0078125f) * 0.0078125f;
            }
}

extern "C" void kernel_launch(void* const* d_in, const int* in_sizes, int n_in,
                              void* d_out, int out_size, void* d_ws, size_t ws_size,
                              hipStream_t stream) {
    const float* x = (const float*)d_in[0];     // (32,112,112,64) fp32 NHWC
    const float* w = (const float*)d_in[1];     // (3,3,64,128) fp32 HWIO
    float* out = (float*)d_out;                 // (32,112,112,128) fp32

    short* bp = (short*)d_ws;                   // 147456 B packed weights
    const size_t BP_BYTES = 147456;
    const size_t XQ_BYTES = (size_t)NIMG * H * W * CI * 2;   // 51,380,224 B
    quant_pack_w<<<288, 256, 0, stream>>>(w, bp);

    if (ws_size >= BP_BYTES + XQ_BYTES) {
        short* xqp = (short*)((char*)d_ws + BP_BYTES);
        quant_x<<<12544, 256, 0, stream>>>(x, xqp);          // 12544*256*8 == 25690112
        conv1r<<<NIMG * H, 256, 0, stream>>>(xqp, bp, out);  // 3584 blocks
    } else {
        conv_fb<<<NIMG * H, 256, 0, stream>>>(x, bp, out);
    }
}

// Round 2
// 306.442 us; speedup vs baseline: 1.1104x; 1.1104x over previous
//
#include <hip/hip_runtime.h>

// Problem constants
#define NIMG 32
#define H 112
#define W 112
#define CI 64
#define CO 128
// K = 3*3*64 = 576 -> 9 K-steps of 64 (i8 MFMA), CI==64 fits one step per tap

typedef __attribute__((ext_vector_type(8))) __bf16 bf16x8;
typedef __attribute__((ext_vector_type(4))) float f32x4;
typedef __attribute__((ext_vector_type(4))) short short4v;
typedef __attribute__((ext_vector_type(4))) int int4v;
typedef __attribute__((ext_vector_type(2))) int int2v;

// ---- fixed-point quantizers ----
// bf16-int variant (kept for fallback path)
__device__ __forceinline__ short q8bits(float v) {
    float t = rintf(v * 128.0f);              // round-half-even == np.round
    t = fminf(fmaxf(t, -128.0f), 127.0f);
    union { float f; unsigned u; } cv; cv.f = t;
    return (short)(cv.u >> 16);               // exact fp32->bf16 (int-valued)
}
// int variant: returns integer in [-128,127]
__device__ __forceinline__ int q8i(float v) {
    float t = rintf(v * 128.0f);
    t = fminf(fmaxf(t, -128.0f), 127.0f);
    return (int)t;
}

// ---------------- i8 weight pack ----------------
// Weights HWIO [576][128] fp32 -> i8 MFMA B-frag order for 16x16x64:
// bp[((kk*8 + nt)*64 + l)*16 + j] = q(w[(kk*64 + (l>>4)*16 + j)*128 + nt*16 + (l&15)])
// kk=0..8 K-steps, nt=0..7 co-tiles, l=lane, j=byte within 16B fragment.
__global__ __launch_bounds__(256) void quant_pack_w_i8(const float* __restrict__ w,
                                                       signed char* __restrict__ bp) {
    int idx = blockIdx.x * 256 + threadIdx.x;   // grid sized exactly 73728
    int j  = idx & 15;
    int l  = (idx >> 4) & 63;
    int nt = (idx >> 10) & 7;
    int kk = idx >> 13;
    int k = kk * 64 + (l >> 4) * 16 + j;
    int n = nt * 16 + (l & 15);
    bp[idx] = (signed char)q8i(w[k * CO + n]);
}

// ---------------- activation prepass: fp32 NHWC -> i8 NHWC ----------------
__global__ __launch_bounds__(256) void quant_x_i8(const float* __restrict__ x,
                                                  signed char* __restrict__ xq) {
    size_t i = ((size_t)blockIdx.x * 256 + threadIdx.x) * 8;
    float4 v0 = *(const float4*)&x[i];
    float4 v1 = *(const float4*)&x[i + 4];
    int b0 = (q8i(v0.x) & 255) | ((q8i(v0.y) & 255) << 8) |
             ((q8i(v0.z) & 255) << 16) | (q8i(v0.w) << 24);
    int b1 = (q8i(v1.x) & 255) | ((q8i(v1.y) & 255) << 8) |
             ((q8i(v1.z) & 255) << 16) | (q8i(v1.w) << 24);
    int2v p; p.x = b0; p.y = b1;
    *(int2v*)&xq[i] = p;
}

// ---------------- Main conv (i8): 1 output row per block, 4 waves ----------------
// Wave w: 112 m (whole row) x 32 co (co quarter = w*32), acc[7][2] i32 = 56 VGPRs.
// All 18 B-fragments (9 kk x 2 nt, 16B each = 72 VGPRs) prefetched to registers
// BEFORE the barrier -> compute loop is pure ds_read_b128 + MFMA, no global latency.
// LDS: 3 input rows x 114 cols x 64ci i8 = 21888 B, linear layout (no swizzle
// needed: col stride 64B -> A-reads partition 32 banks uniformly, 8 lanes/4-bank grp).
// DMA: interior cols 1..112 = 7x1024B contiguous chunks per row, linear both sides.
#define RB 7296   // 114*64 bytes per row slot

__global__ __launch_bounds__(256, 3) void conv_i8(const signed char* __restrict__ xq,
                                                  const signed char* __restrict__ bp,
                                                  float* __restrict__ out) {
    __shared__ __align__(16) signed char xs[3 * RB];   // 21888 B
    int bid0 = blockIdx.x;
    int bid = (bid0 & 7) * 448 + (bid0 >> 3);   // XCD swizzle (3584 % 8 == 0, bijective)
    int n = bid / H;
    int h = bid - n * H;
    int tid  = threadIdx.x;
    int lane = tid & 63;
    int wave = tid >> 6;

    // ---- stage: DMA 3 input rows (7 x 1KB chunks each), split over waves ----
    const signed char* base = xq + (size_t)(n * H) * (W * CI);
    for (int idx = wave; idx < 21; idx += 4) {        // wave-uniform row/i
        int row = idx / 7;
        int i = idx - row * 7;
        int hr = h - 1 + row;
        if ((unsigned)hr < (unsigned)H) {
            const signed char* g = base + (size_t)hr * (W * CI) + i * 1024 + lane * 16;
            __builtin_amdgcn_global_load_lds(
                (const __attribute__((address_space(1))) void*)g,
                (__attribute__((address_space(3))) void*)(xs + row * RB + 64 + i * 1024),
                16, 0, 0);
        }
    }

    // ---- B prefetch: all 18 fragments to registers (independent of LDS) ----
    int nt0 = wave * 2;
    const int4v* bp4 = (const int4v*)bp;
    int4v breg[9][2];
    #pragma unroll
    for (int kk = 0; kk < 9; ++kk) {
        breg[kk][0] = bp4[(kk * 8 + nt0    ) * 64 + lane];
        breg[kk][1] = bp4[(kk * 8 + nt0 + 1) * 64 + lane];
    }

    // ---- zero boundary rows + halo cols ----
    if (h == 0)
        for (int t = tid; t < 456; t += 256) *(int4v*)&xs[t * 16] = (int4v){0, 0, 0, 0};
    if (h == H - 1)
        for (int t = tid; t < 456; t += 256) *(int4v*)&xs[2 * RB + t * 16] = (int4v){0, 0, 0, 0};
    if (tid < 24) {                           // cols 0 and 113, 3 rows, 64B each
        int r2 = tid >> 3, ci = tid & 7;
        int c = (ci & 4) ? 113 : 0;
        *(int4v*)&xs[r2 * RB + c * 64 + (ci & 3) * 16] = (int4v){0, 0, 0, 0};
    }
    __syncthreads();

    // ---- implicit GEMM: wave = 112 m x 32 co, K=576 in 9 steps of 64 ----
    int lane15 = lane & 15;
    int hi     = lane >> 4;                   // 0..3 -> ci offset hi*16

    int4v acc[7][2];
    #pragma unroll
    for (int mt = 0; mt < 7; ++mt) {
        acc[mt][0] = (int4v){0, 0, 0, 0};
        acc[mt][1] = (int4v){0, 0, 0, 0};
    }

    #pragma unroll
    for (int r = 0; r < 3; ++r) {
        #pragma unroll
        for (int s = 0; s < 3; ++s) {
            int kk = r * 3 + s;
            int abase = r * RB + (s + lane15) * 64 + hi * 16;
            #pragma unroll
            for (int mt = 0; mt < 7; ++mt) {
                int4v a = *(const int4v*)&xs[abase + mt * 1024];
                acc[mt][0] = __builtin_amdgcn_mfma_i32_16x16x64_i8(a, breg[kk][0], acc[mt][0], 0, 0, 0);
                acc[mt][1] = __builtin_amdgcn_mfma_i32_16x16x64_i8(a, breg[kk][1], acc[mt][1], 0, 0, 0);
            }
        }
    }

    // ---- epilogue: out = floor(S/128)/128, exact in int ----
    float* orow = out + (size_t)((n * H + h) * W) * CO;
    int co0  = wave * 32 + lane15;
    int rowb = hi * 4;
    #pragma unroll
    for (int mt = 0; mt < 7; ++mt)
        #pragma unroll
        for (int t = 0; t < 2; ++t)
            #pragma unroll
            for (int rg = 0; rg < 4; ++rg) {
                int m = mt * 16 + rowb + rg;
                orow[m * CO + co0 + t * 16] =
                    (float)(acc[mt][t][rg] >> 7) * 0.0078125f;
            }
}

// ---------------- bf16 weight pack (fallback path only) ----------------
__global__ __launch_bounds__(256) void quant_pack_w(const float* __restrict__ w,
                                                    short* __restrict__ bp) {
    int idx = blockIdx.x * 256 + threadIdx.x;   // grid sized exactly 73728
    int j    = idx & 7;
    int lane = (idx >> 3) & 63;
    int nt   = (idx >> 9) & 7;
    int kt   = idx >> 12;
    int k = kt * 32 + (lane >> 4) * 8 + j;
    int n = nt * 16 + (lane & 15);
    bp[idx] = q8bits(w[k * CO + n]);
}

// ---------------- R1 fallback (ws too small for xq): verified exact ----------------
#define LDSW 114
#define LDST 72
__global__ __launch_bounds__(256, 3) void conv_fb(const float* __restrict__ x,
                                                  const short* __restrict__ bp,
                                                  float* __restrict__ out) {
    __shared__ short xs[3 * LDSW * LDST];
    int bid = blockIdx.x;
    int n = bid / H;
    int h = bid - n * H;
    int tid = threadIdx.x;
    const float* xin = x + (size_t)n * (H * W * CI);
    for (int r = 0; r < 3; ++r) {
        int hrow = h + r - 1;
        bool rowok = ((unsigned)hrow < (unsigned)H);
        const float* srow = xin + (size_t)hrow * (W * CI);
        for (int t = tid; t < LDSW * 16; t += 256) {
            int c = t >> 4;
            int ci4 = (t & 15) << 2;
            int wcol = c - 1;
            float4 v = {0.f, 0.f, 0.f, 0.f};
            if (rowok && (unsigned)wcol < (unsigned)W)
                v = *(const float4*)&srow[wcol * CI + ci4];
            short4v sv;
            sv.x = q8bits(v.x); sv.y = q8bits(v.y);
            sv.z = q8bits(v.z); sv.w = q8bits(v.w);
            *(short4v*)&xs[(r * LDSW + c) * LDST + ci4] = sv;
        }
    }
    __syncthreads();
    int lane = tid & 63;
    int wave = tid >> 6;
    int laneoff = (lane & 15) * LDST + (lane >> 4) * 8;
    const bf16x8* bfr = (const bf16x8*)bp;
    int nt0 = wave * 2;
    f32x4 acc[7][2];
    #pragma unroll
    for (int mt = 0; mt < 7; ++mt) {
        acc[mt][0] = (f32x4){0.f, 0.f, 0.f, 0.f};
        acc[mt][1] = (f32x4){0.f, 0.f, 0.f, 0.f};
    }
    #pragma unroll
    for (int kk = 0; kk < 18; ++kk) {
        int rs = kk >> 1;
        int r = rs / 3;
        int s = rs - r * 3;
        bf16x8 b0 = bfr[(kk * 8 + nt0    ) * 64 + lane];
        bf16x8 b1 = bfr[(kk * 8 + nt0 + 1) * 64 + lane];
        int abase = (r * LDSW + s) * LDST + (kk & 1) * 32 + laneoff;
        #pragma unroll
        for (int mt = 0; mt < 7; ++mt) {
            bf16x8 a = *(const bf16x8*)&xs[abase + mt * 16 * LDST];
            acc[mt][0] = __builtin_amdgcn_mfma_f32_16x16x32_bf16(a, b0, acc[mt][0], 0, 0, 0);
            acc[mt][1] = __builtin_amdgcn_mfma_f32_16x16x32_bf16(a, b1, acc[mt][1], 0, 0, 0);
        }
    }
    float* orow = out + (size_t)(n * H + h) * (W * CO);
    int colc = wave * 32 + (lane & 15);
    int rowb = (lane >> 4) * 4;
    #pragma unroll
    for (int mt = 0; mt < 7; ++mt)
        #pragma unroll
        for (int t2 = 0; t2 < 2; ++t2)
            #pragma unroll
            for (int rg = 0; rg < 4; ++rg) {
                int m = mt * 16 + rowb + rg;
                orow[m * CO + colc + t2 * 16] =
                    floorf(acc[mt][t2][rg] * 0.0078125f) * 0.0078125f;
            }
}

extern "C" void kernel_launch(void* const* d_in, const int* in_sizes, int n_in,
                              void* d_out, int out_size, void* d_ws, size_t ws_size,
                              hipStream_t stream) {
    const float* x = (const float*)d_in[0];     // (32,112,112,64) fp32 NHWC
    const float* w = (const float*)d_in[1];     // (3,3,64,128) fp32 HWIO
    float* out = (float*)d_out;                 // (32,112,112,128) fp32

    const size_t BPI8_BYTES = 73728;            // 576*128 i8 packed weights
    const size_t XQ8_BYTES  = (size_t)NIMG * H * W * CI;   // 25,690,112 B

    if (ws_size >= BPI8_BYTES + XQ8_BYTES) {
        signed char* bp8 = (signed char*)d_ws;
        signed char* xq8 = (signed char*)d_ws + BPI8_BYTES;
        quant_pack_w_i8<<<288, 256, 0, stream>>>(w, bp8);
        quant_x_i8<<<12544, 256, 0, stream>>>(x, xq8);     // 12544*256*8 == 25690112
        conv_i8<<<NIMG * H, 256, 0, stream>>>(xq8, bp8, out);  // 3584 blocks
    } else {
        short* bp = (short*)d_ws;               // 147456 B bf16 packed weights
        quant_pack_w<<<288, 256, 0, stream>>>(w, bp);
        conv_fb<<<NIMG * H, 256, 0, stream>>>(x, bp, out);
    }
}